// Round 5
// baseline (1404.653 us; speedup 1.0000x reference)
//
#include <hip/hip_runtime.h>
#include <hip/hip_bf16.h>

#define NTOK 32768
#define KEMB 4096
#define DDIM 256
#define DECAYF 0.99f
#define EPSF 1e-5f
#define KSPLIT 512   // 2-term fp16 split: [Xh|Xl] . [Ch|Ch]

// ---------------- workspace layout (BYTE offsets) ----------------
#define B_AHAT  0ull          // 32768*512 f16 = 33554432 B  [Xh|Xl]
#define B_BHAT  33554432ull   // 4096*512 f16  = 4194304 B   [Ch|Ch]
#define B_PART  37748736ull   // 32768*64 float4 = 33554432 B per-64col-chunk (b1,b2,idx)
#define B_CE    71303168ull   // 4096 f32
#define B_CNTI  71319552ull   // 4096 int: integer counts (atomic slot counters)
#define B_CSP   71335936ull   // 4096 f32: cs_pre
#define B_OFFS  71352320ull   // 4096 int: CSR offsets
#define B_NPTR  71368704ull   // f32 n ; +4 int flagCount
#define B_TIDX  71368768ull   // 32768 int: per-token argmin
#define B_FLIST 71499840ull   // 32768 int: flagged tokens
#define B_SLOT  71630912ull   // 32768 int: slot of token within its cluster
#define B_TLIST 71761984ull   // 32768 int: CSR token list
// total ~71.9 MB

// ---------------- output layout (float offsets) ----------------
#define OFF_Q  0ull                 // quantized  [32768,256]
#define OFF_E  8388608ull           // encodings  [32768,4096]
#define OFF_CB 142606336ull         // new_codebook [4096,256]
#define OFF_W  143654912ull         // new_ema_w    [4096,256]
#define OFF_CS 144703488ull         // cs [4096]

typedef __attribute__((ext_vector_type(8))) _Float16 f16x8;
typedef __attribute__((ext_vector_type(4))) float f32x4;

// ---- split fp32 -> (hi, lo) fp16, Ahat = [Xh | Xl] along K ----
__global__ __launch_bounds__(256) void splitA_kernel(const float* __restrict__ x,
                                                     _Float16* __restrict__ Ahat) {
    int gid = blockIdx.x * 256 + threadIdx.x;   // 0 .. 32768*32-1
    int i = gid >> 5;
    int c = gid & 31;                           // 8-elem chunk
    const float* xp = x + (size_t)i * DDIM + c * 8;
    f16x8 hi, lo;
    #pragma unroll
    for (int t = 0; t < 8; ++t) {
        float v = xp[t];
        _Float16 h = (_Float16)v;
        _Float16 l = (_Float16)(v - (float)h);
        hi[t] = h;
        lo[t] = l;
    }
    _Float16* row = Ahat + (size_t)i * KSPLIT + c * 8;
    *(f16x8*)(row)       = hi;
    *(f16x8*)(row + 256) = lo;
}

// ---- Bhat = [Ch | Ch] along K; also emits ce[j] = ||c_j||^2 (fp32) ----
__global__ __launch_bounds__(256) void splitB_kernel(const float* __restrict__ cb,
                                                     _Float16* __restrict__ Bhat,
                                                     float* __restrict__ ce) {
    int gid = blockIdx.x * 256 + threadIdx.x;   // 0 .. 4096*32-1
    int j = gid >> 5;
    int c = gid & 31;
    const float* cp = cb + (size_t)j * DDIM + c * 8;
    f16x8 hi;
    float nrm = 0.0f;
    #pragma unroll
    for (int t = 0; t < 8; ++t) {
        float v = cp[t];
        nrm = fmaf(v, v, nrm);
        hi[t] = (_Float16)v;
    }
    _Float16* row = Bhat + (size_t)j * KSPLIT + c * 8;
    *(f16x8*)(row)       = hi;
    *(f16x8*)(row + 256) = hi;
    #pragma unroll
    for (int m = 16; m > 0; m >>= 1) nrm += __shfl_xor(nrm, m, 32);
    if (c == 0) ce[j] = nrm;
}

// ---- fp16 MFMA GEMM (M=32768, N=4096, K=512) with fused per-row argmin.
// 128x128 tile, BK=64, global_load_lds width-16, XOR-swizzled chunk staging.
// Grid: x = nb (fast) so 32 consecutive blocks share one A-tile (L2-hot).
__global__ __launch_bounds__(256) void gemm_argmin_kernel(
        const _Float16* __restrict__ Ahat,
        const _Float16* __restrict__ Bhat,
        const float* __restrict__ ceg,
        float4* __restrict__ part) {
    __shared__ _Float16 As[128 * 64];   // 16 KB
    __shared__ _Float16 Bs[128 * 64];   // 16 KB
    const int tid  = threadIdx.x;
    const int lane = tid & 63;
    const int wave = tid >> 6;
    const int wm = wave >> 1, wn = wave & 1;  // 2x2 wave grid, 64x64 per wave
    const int nb = blockIdx.x, mb = blockIdx.y;   // nb fastest -> A-tile reuse
    const int col = lane & 15, q = lane >> 4;
    const int cswz = q ^ (col & 7);           // reader chunk swizzle base

    const int srow = tid >> 3;
    const int sswz = (tid & 7) ^ (srow & 7);
    const _Float16* ag = Ahat + (size_t)(mb * 128 + srow) * KSPLIT + sswz * 8;
    const _Float16* bg = Bhat + (size_t)(nb * 128 + srow) * KSPLIT + sswz * 8;

    f32x4 zero = {0.f, 0.f, 0.f, 0.f};
    f32x4 acc[4][4];
    #pragma unroll
    for (int i = 0; i < 4; ++i)
        #pragma unroll
        for (int j = 0; j < 4; ++j) acc[i][j] = zero;

    for (int kt = 0; kt < KSPLIT / 64; ++kt) {
        __syncthreads();
        #pragma unroll
        for (int n = 0; n < 4; ++n) {
            __builtin_amdgcn_global_load_lds(
                (const __attribute__((address_space(1))) void*)(ag + (size_t)n * 32 * KSPLIT + kt * 64),
                (__attribute__((address_space(3))) void*)(As + n * 2048 + tid * 8), 16, 0, 0);
            __builtin_amdgcn_global_load_lds(
                (const __attribute__((address_space(1))) void*)(bg + (size_t)n * 32 * KSPLIT + kt * 64),
                (__attribute__((address_space(3))) void*)(Bs + n * 2048 + tid * 8), 16, 0, 0);
        }
        __syncthreads();

        const f16x8* Av = (const f16x8*)As;
        const f16x8* Bv = (const f16x8*)Bs;
        #pragma unroll
        for (int ks = 0; ks < 2; ++ks) {
            f16x8 a[4], b[4];
            #pragma unroll
            for (int i = 0; i < 4; ++i)
                a[i] = Av[(wm * 64 + i * 16 + col) * 8 + (cswz ^ (ks * 4))];
            #pragma unroll
            for (int j = 0; j < 4; ++j)
                b[j] = Bv[(wn * 64 + j * 16 + col) * 8 + (cswz ^ (ks * 4))];
            #pragma unroll
            for (int i = 0; i < 4; ++i)
                #pragma unroll
                for (int j = 0; j < 4; ++j)
                    acc[i][j] = __builtin_amdgcn_mfma_f32_16x16x32_f16(a[i], b[j], acc[i][j], 0, 0, 0);
        }
    }

    // epilogue: s = ||c||^2 - 2*dot. C/D layout: col = lane&15, row = q*4+reg.
    float ce_j[4];
    #pragma unroll
    for (int j = 0; j < 4; ++j) ce_j[j] = ceg[nb * 128 + wn * 64 + j * 16 + col];

    #pragma unroll
    for (int i = 0; i < 4; ++i) {
        #pragma unroll
        for (int r = 0; r < 4; ++r) {
            float b1 = 3.4e38f, b2 = 3.4e38f;
            int i1 = 0x7fffffff;
            #pragma unroll
            for (int j = 0; j < 4; ++j) {
                float s = ce_j[j] - 2.0f * acc[i][j][r];
                int n = nb * 128 + wn * 64 + j * 16 + col;
                if (s < b1) { b2 = b1; b1 = s; i1 = n; }
                else if (s < b2) { b2 = s; }
            }
            #pragma unroll
            for (int m = 1; m < 16; m <<= 1) {
                float ob1 = __shfl_xor(b1, m, 16);
                float ob2 = __shfl_xor(b2, m, 16);
                int   oi  = __shfl_xor(i1, m, 16);
                bool take = (ob1 < b1) || (ob1 == b1 && oi < i1);
                float nb2 = take ? fminf(b1, ob2) : fminf(b2, ob1);
                if (take) { b1 = ob1; i1 = oi; }
                b2 = nb2;
            }
            if (col == i * 4 + r) {   // unique writer lane per (q,i,r)
                int mrow = mb * 128 + wm * 64 + i * 16 + q * 4 + r;
                float4 p;
                p.x = b1; p.y = b2; p.z = __int_as_float(i1); p.w = 0.0f;
                part[(size_t)mrow * 64 + nb * 2 + wn] = p;
            }
        }
    }
}

// ---- merge 64 column-chunk partials per row; flag near-ties ----
__global__ __launch_bounds__(256) void argmin_reduce_kernel(
        const float4* __restrict__ part,
        int* __restrict__ tokIdx,
        int* __restrict__ flist,
        int* __restrict__ flagCount) {
    int row = blockIdx.x * 4 + (threadIdx.x >> 6);
    int lane = threadIdx.x & 63;
    float4 p = part[(size_t)row * 64 + lane];
    float b1 = p.x, b2 = p.y;
    int i1 = __float_as_int(p.z);
    #pragma unroll
    for (int m = 1; m < 64; m <<= 1) {
        float ob1 = __shfl_xor(b1, m);
        float ob2 = __shfl_xor(b2, m);
        int   oi  = __shfl_xor(i1, m);
        bool take = (ob1 < b1) || (ob1 == b1 && oi < i1);
        float nb2 = take ? fminf(b1, ob2) : fminf(b2, ob1);
        if (take) { b1 = ob1; i1 = oi; }
        b2 = nb2;
    }
    if (lane == 0) {
        tokIdx[row] = i1;
        if (b2 - b1 < 0.0625f) {   // near-tie vs fp16-split noise (~6e-3): refine
            int slot = atomicAdd(flagCount, 1);
            flist[slot] = row;
        }
    }
}

// ---- fp64 exact re-resolution of flagged tokens ----
__global__ __launch_bounds__(256) void refine_kernel(const float* __restrict__ xg,
                                                     const float* __restrict__ cb,
                                                     int* __restrict__ tokIdx,
                                                     const int* __restrict__ flagList,
                                                     const int* __restrict__ flagCount) {
    __shared__ double xs[256];
    __shared__ double rb[256];
    __shared__ int    ri[256];
    int nf = *flagCount;
    for (int f = blockIdx.x; f < nf; f += gridDim.x) {
        int tok = flagList[f];
        __syncthreads();
        xs[threadIdx.x] = (double)xg[(size_t)tok * DDIM + threadIdx.x];
        __syncthreads();
        double best = 1e300;
        int bi = 0x7fffffff;
        for (int kk = 0; kk < KEMB / 256; ++kk) {
            int k = kk * 256 + threadIdx.x;
            const float* e = cb + (size_t)k * DDIM;
            double s = 0.0;
            for (int d4 = 0; d4 < DDIM / 4; ++d4) {
                float4 e4 = *(const float4*)(e + d4 * 4);
                double e0 = (double)e4.x, e1 = (double)e4.y;
                double e2 = (double)e4.z, e3 = (double)e4.w;
                s += e0 * (e0 - 2.0 * xs[d4 * 4 + 0]) + e1 * (e1 - 2.0 * xs[d4 * 4 + 1])
                   + e2 * (e2 - 2.0 * xs[d4 * 4 + 2]) + e3 * (e3 - 2.0 * xs[d4 * 4 + 3]);
            }
            if (s < best) { best = s; bi = k; }
        }
        rb[threadIdx.x] = best;
        ri[threadIdx.x] = bi;
        __syncthreads();
        if (threadIdx.x == 0) {
            double b = rb[0]; int i1 = ri[0];
            for (int c = 1; c < 256; ++c) {
                if (rb[c] < b || (rb[c] == b && ri[c] < i1)) { b = rb[c]; i1 = ri[c]; }
            }
            tokIdx[tok] = i1;
        }
        __syncthreads();
    }
}

// ---- CSR pass 1: slot assignment + integer counts (32k small atomics) ----
__global__ __launch_bounds__(256) void tokslot_kernel(const int* __restrict__ tokIdx,
                                                      int* __restrict__ countsI,
                                                      int* __restrict__ slotOf) {
    int t = blockIdx.x * 256 + threadIdx.x;
    int k = tokIdx[t];
    slotOf[t] = atomicAdd(countsI + k, 1);
}

// ---- CSR pass 2: exclusive scan of countsI[4096] -> offs ----
__global__ __launch_bounds__(256) void scan_kernel(const int* __restrict__ countsI,
                                                   int* __restrict__ offs) {
    __shared__ int part[256];
    __shared__ int pref[257];
    int tid = threadIdx.x;
    int local[16];
    int s = 0;
    #pragma unroll
    for (int i = 0; i < 16; ++i) { local[i] = countsI[tid * 16 + i]; s += local[i]; }
    part[tid] = s;
    __syncthreads();
    if (tid == 0) {
        pref[0] = 0;
        for (int i = 0; i < 256; ++i) pref[i + 1] = pref[i] + part[i];
    }
    __syncthreads();
    int run = pref[tid];
    #pragma unroll
    for (int i = 0; i < 16; ++i) { offs[tid * 16 + i] = run; run += local[i]; }
}

// ---- CSR pass 3: fill token list (no atomics) ----
__global__ __launch_bounds__(256) void filllist_kernel(const int* __restrict__ tokIdx,
                                                       const int* __restrict__ offs,
                                                       const int* __restrict__ slotOf,
                                                       int* __restrict__ tlist) {
    int t = blockIdx.x * 256 + threadIdx.x;
    int k = tokIdx[t];
    tlist[offs[k] + slotOf[t]] = t;
}

// ---- cs_pre = ema_cs*decay + (1-decay)*counts ; n = sum(cs_pre) ----
__global__ __launch_bounds__(256) void cs_kernel(const float* __restrict__ ema_cs,
                                                 const int* __restrict__ countsI,
                                                 float* __restrict__ cs_pre,
                                                 float* __restrict__ nptr) {
    int k = blockIdx.x * 256 + threadIdx.x;
    float c = ema_cs[k] * DECAYF + (1.0f - DECAYF) * (float)countsI[k];
    cs_pre[k] = c;
    float s = c;
    #pragma unroll
    for (int o = 32; o > 0; o >>= 1) s += __shfl_down(s, o);
    __shared__ float red[4];
    int lane = threadIdx.x & 63, w = threadIdx.x >> 6;
    if (lane == 0) red[w] = s;
    __syncthreads();
    if (threadIdx.x == 0) atomicAdd(nptr, red[0] + red[1] + red[2] + red[3]);
}

// ---- per-token scatter: full one-hot row + quantized row (pure streaming) ----
__global__ __launch_bounds__(256) void scatter_kernel(const float* __restrict__ cb,
                                                      const int* __restrict__ tokIdx,
                                                      float* __restrict__ quant,
                                                      float* __restrict__ enc) {
    int tok = blockIdx.x;
    int tid = threadIdx.x;
    int k = tokIdx[tok];
    float4* er = (float4*)(enc + (size_t)tok * KEMB);
    int kf4 = k >> 2, kc = k & 3;
    #pragma unroll
    for (int v = 0; v < 4; ++v) {
        int f4 = v * 256 + tid;
        float4 val = {0.f, 0.f, 0.f, 0.f};
        if (f4 == kf4) ((float*)&val)[kc] = 1.0f;
        er[f4] = val;
    }
    if (tid < 64) {
        float4 e = *(const float4*)(cb + (size_t)k * DDIM + tid * 4);
        *(float4*)(quant + (size_t)tok * DDIM + tid * 4) = e;
    }
}

// ---- dw gather + fused epilogue: one block (64 thr) per cluster.
// dw_k = sum of x rows in cluster; never materialized to memory.
__global__ __launch_bounds__(64) void dwgather_epi_kernel(
        const float* __restrict__ xg,
        const int* __restrict__ tlist,
        const int* __restrict__ offs,
        const int* __restrict__ countsI,
        const float* __restrict__ ema_w,
        const float* __restrict__ cs_pre,
        const float* __restrict__ nptr,
        float* __restrict__ new_w,
        float* __restrict__ new_cb,
        float* __restrict__ cs_out) {
    int k = blockIdx.x;
    int lane = threadIdx.x;
    int nt = countsI[k];
    int off = offs[k];
    float4 acc = {0.f, 0.f, 0.f, 0.f};
    for (int i = 0; i < nt; ++i) {
        int t = tlist[off + i];
        float4 xv = *(const float4*)(xg + (size_t)t * DDIM + lane * 4);
        acc.x += xv.x; acc.y += xv.y; acc.z += xv.z; acc.w += xv.w;
    }
    float n = *nptr;
    float cs = (cs_pre[k] + EPSF) / (n + (float)KEMB * EPSF) * n;
    float4 w4 = *(const float4*)(ema_w + (size_t)k * DDIM + lane * 4);
    float4 nw;
    nw.x = w4.x * DECAYF + (1.0f - DECAYF) * acc.x;
    nw.y = w4.y * DECAYF + (1.0f - DECAYF) * acc.y;
    nw.z = w4.z * DECAYF + (1.0f - DECAYF) * acc.z;
    nw.w = w4.w * DECAYF + (1.0f - DECAYF) * acc.w;
    *(float4*)(new_w + (size_t)k * DDIM + lane * 4) = nw;
    float4 nc;
    nc.x = nw.x / cs; nc.y = nw.y / cs; nc.z = nw.z / cs; nc.w = nw.w / cs;
    *(float4*)(new_cb + (size_t)k * DDIM + lane * 4) = nc;
    if (lane == 0) cs_out[k] = cs;
}

extern "C" void kernel_launch(void* const* d_in, const int* in_sizes, int n_in,
                              void* d_out, int out_size, void* d_ws, size_t ws_size,
                              hipStream_t stream) {
    const float* xg     = (const float*)d_in[0];   // [32768,256]
    const float* cbg    = (const float*)d_in[1];   // [4096,256]
    const float* ema_w  = (const float*)d_in[2];   // [4096,256]
    const float* ema_cs = (const float*)d_in[3];   // [4096]

    float* out = (float*)d_out;
    unsigned char* wsb = (unsigned char*)d_ws;

    float* quant  = out + OFF_Q;
    float* enc    = out + OFF_E;
    float* new_cb = out + OFF_CB;
    float* new_w  = out + OFF_W;
    float* cs_out = out + OFF_CS;

    _Float16* Ahat = (_Float16*)(wsb + B_AHAT);
    _Float16* Bhat = (_Float16*)(wsb + B_BHAT);
    float4* part   = (float4*)(wsb + B_PART);
    float* ce      = (float*)(wsb + B_CE);
    int*   countsI = (int*)(wsb + B_CNTI);
    float* cs_pre  = (float*)(wsb + B_CSP);
    int*   offs    = (int*)(wsb + B_OFFS);
    float* nptr    = (float*)(wsb + B_NPTR);
    int*   flagCnt = (int*)(wsb + B_NPTR + 4);
    int*   tokIdx  = (int*)(wsb + B_TIDX);
    int*   flist   = (int*)(wsb + B_FLIST);
    int*   slotOf  = (int*)(wsb + B_SLOT);
    int*   tlist   = (int*)(wsb + B_TLIST);

    // zero-init (d_out / d_ws are poisoned with 0xAA before every call).
    hipMemsetAsync(countsI, 0, KEMB * sizeof(int), stream);
    hipMemsetAsync(nptr, 0, 8, stream);                        // n + flagCount

    splitA_kernel<<<(NTOK * 32) / 256, 256, 0, stream>>>(xg, Ahat);
    splitB_kernel<<<(KEMB * 32) / 256, 256, 0, stream>>>(cbg, Bhat, ce);
    gemm_argmin_kernel<<<dim3(KEMB / 128, NTOK / 128), 256, 0, stream>>>(Ahat, Bhat, ce, part);
    argmin_reduce_kernel<<<NTOK / 4, 256, 0, stream>>>(part, tokIdx, flist, flagCnt);
    refine_kernel<<<256, 256, 0, stream>>>(xg, cbg, tokIdx, flist, flagCnt);
    tokslot_kernel<<<NTOK / 256, 256, 0, stream>>>(tokIdx, countsI, slotOf);
    cs_kernel<<<KEMB / 256, 256, 0, stream>>>(ema_cs, countsI, cs_pre, nptr);
    scan_kernel<<<1, 256, 0, stream>>>(countsI, offs);
    filllist_kernel<<<NTOK / 256, 256, 0, stream>>>(tokIdx, offs, slotOf, tlist);
    scatter_kernel<<<NTOK, 256, 0, stream>>>(cbg, tokIdx, quant, enc);
    dwgather_epi_kernel<<<KEMB, 64, 0, stream>>>(xg, tlist, offs, countsI, ema_w,
                                                 cs_pre, nptr, new_w, new_cb, cs_out);
}

// Round 6
// 1032.235 us; speedup vs baseline: 1.3608x; 1.3608x over previous
//
#include <hip/hip_runtime.h>
#include <hip/hip_bf16.h>

#define NTOK 32768
#define KEMB 4096
#define DDIM 256
#define DECAYF 0.99f
#define EPSF 1e-5f
#define KSPLIT 512   // 2-term fp16 split: [Xh|Xl] . [Ch|Ch]

// ---------------- workspace layout (BYTE offsets) ----------------
#define B_AHAT  0ull          // 32768*512 f16 = 33554432 B  [Xh|Xl]
#define B_BHAT  33554432ull   // 4096*512 f16  = 4194304 B   [Ch|Ch]
#define B_PART  37748736ull   // 32768*64 float4 = 33554432 B per-64col-chunk (b1,b2,idx)
#define B_CE    71303168ull   // 4096 f32
#define B_CNTI  71319552ull   // 4096 int: integer counts (atomic slot counters)
#define B_CSP   71335936ull   // 4096 f32: cs_pre
#define B_OFFS  71352320ull   // 4096 int: CSR offsets
#define B_NPTR  71368704ull   // f32 n ; +4 int flagCount
#define B_TIDX  71368768ull   // 32768 int: per-token argmin
#define B_FLIST 71499840ull   // 32768 int: flagged tokens
#define B_SLOT  71630912ull   // 32768 int: slot of token within its cluster
#define B_TLIST 71761984ull   // 32768 int: CSR token list
#define B_DW    71893056ull   // 4096*256 f32 = 4194304 B segment sums
// total ~76.1 MB

// ---------------- output layout (float offsets) ----------------
#define OFF_Q  0ull                 // quantized  [32768,256]
#define OFF_E  8388608ull           // encodings  [32768,4096]
#define OFF_CB 142606336ull         // new_codebook [4096,256]
#define OFF_W  143654912ull         // new_ema_w    [4096,256]
#define OFF_CS 144703488ull         // cs [4096]

typedef __attribute__((ext_vector_type(8))) _Float16 f16x8;
typedef __attribute__((ext_vector_type(4))) float f32x4;

// ---- split fp32 -> (hi, lo) fp16, Ahat = [Xh | Xl] along K ----
__global__ __launch_bounds__(256) void splitA_kernel(const float* __restrict__ x,
                                                     _Float16* __restrict__ Ahat) {
    int gid = blockIdx.x * 256 + threadIdx.x;   // 0 .. 32768*32-1
    int i = gid >> 5;
    int c = gid & 31;                           // 8-elem chunk
    const float* xp = x + (size_t)i * DDIM + c * 8;
    f16x8 hi, lo;
    #pragma unroll
    for (int t = 0; t < 8; ++t) {
        float v = xp[t];
        _Float16 h = (_Float16)v;
        _Float16 l = (_Float16)(v - (float)h);
        hi[t] = h;
        lo[t] = l;
    }
    _Float16* row = Ahat + (size_t)i * KSPLIT + c * 8;
    *(f16x8*)(row)       = hi;
    *(f16x8*)(row + 256) = lo;
}

// ---- Bhat = [Ch | Ch] along K; also emits ce[j] = ||c_j||^2 (fp32) ----
__global__ __launch_bounds__(256) void splitB_kernel(const float* __restrict__ cb,
                                                     _Float16* __restrict__ Bhat,
                                                     float* __restrict__ ce) {
    int gid = blockIdx.x * 256 + threadIdx.x;   // 0 .. 4096*32-1
    int j = gid >> 5;
    int c = gid & 31;
    const float* cp = cb + (size_t)j * DDIM + c * 8;
    f16x8 hi;
    float nrm = 0.0f;
    #pragma unroll
    for (int t = 0; t < 8; ++t) {
        float v = cp[t];
        nrm = fmaf(v, v, nrm);
        hi[t] = (_Float16)v;
    }
    _Float16* row = Bhat + (size_t)j * KSPLIT + c * 8;
    *(f16x8*)(row)       = hi;
    *(f16x8*)(row + 256) = hi;
    #pragma unroll
    for (int m = 16; m > 0; m >>= 1) nrm += __shfl_xor(nrm, m, 32);
    if (c == 0) ce[j] = nrm;
}

// ---- fp16 MFMA GEMM (M=32768, N=4096, K=512) with fused per-row argmin.
// 128x128 tile, BK=64, global_load_lds width-16, XOR-swizzled chunk staging.
// Grid: x = nb (fast) so 32 consecutive blocks share one A-tile (L2-hot).
__global__ __launch_bounds__(256) void gemm_argmin_kernel(
        const _Float16* __restrict__ Ahat,
        const _Float16* __restrict__ Bhat,
        const float* __restrict__ ceg,
        float4* __restrict__ part) {
    __shared__ _Float16 As[128 * 64];   // 16 KB
    __shared__ _Float16 Bs[128 * 64];   // 16 KB
    const int tid  = threadIdx.x;
    const int lane = tid & 63;
    const int wave = tid >> 6;
    const int wm = wave >> 1, wn = wave & 1;  // 2x2 wave grid, 64x64 per wave
    const int nb = blockIdx.x, mb = blockIdx.y;   // nb fastest -> A-tile reuse
    const int col = lane & 15, q = lane >> 4;
    const int cswz = q ^ (col & 7);           // reader chunk swizzle base

    const int srow = tid >> 3;
    const int sswz = (tid & 7) ^ (srow & 7);
    const _Float16* ag = Ahat + (size_t)(mb * 128 + srow) * KSPLIT + sswz * 8;
    const _Float16* bg = Bhat + (size_t)(nb * 128 + srow) * KSPLIT + sswz * 8;

    f32x4 zero = {0.f, 0.f, 0.f, 0.f};
    f32x4 acc[4][4];
    #pragma unroll
    for (int i = 0; i < 4; ++i)
        #pragma unroll
        for (int j = 0; j < 4; ++j) acc[i][j] = zero;

    for (int kt = 0; kt < KSPLIT / 64; ++kt) {
        __syncthreads();
        #pragma unroll
        for (int n = 0; n < 4; ++n) {
            __builtin_amdgcn_global_load_lds(
                (const __attribute__((address_space(1))) void*)(ag + (size_t)n * 32 * KSPLIT + kt * 64),
                (__attribute__((address_space(3))) void*)(As + n * 2048 + tid * 8), 16, 0, 0);
            __builtin_amdgcn_global_load_lds(
                (const __attribute__((address_space(1))) void*)(bg + (size_t)n * 32 * KSPLIT + kt * 64),
                (__attribute__((address_space(3))) void*)(Bs + n * 2048 + tid * 8), 16, 0, 0);
        }
        __syncthreads();

        const f16x8* Av = (const f16x8*)As;
        const f16x8* Bv = (const f16x8*)Bs;
        #pragma unroll
        for (int ks = 0; ks < 2; ++ks) {
            f16x8 a[4], b[4];
            #pragma unroll
            for (int i = 0; i < 4; ++i)
                a[i] = Av[(wm * 64 + i * 16 + col) * 8 + (cswz ^ (ks * 4))];
            #pragma unroll
            for (int j = 0; j < 4; ++j)
                b[j] = Bv[(wn * 64 + j * 16 + col) * 8 + (cswz ^ (ks * 4))];
            #pragma unroll
            for (int i = 0; i < 4; ++i)
                #pragma unroll
                for (int j = 0; j < 4; ++j)
                    acc[i][j] = __builtin_amdgcn_mfma_f32_16x16x32_f16(a[i], b[j], acc[i][j], 0, 0, 0);
        }
    }

    // epilogue: s = ||c||^2 - 2*dot. C/D layout: col = lane&15, row = q*4+reg.
    float ce_j[4];
    #pragma unroll
    for (int j = 0; j < 4; ++j) ce_j[j] = ceg[nb * 128 + wn * 64 + j * 16 + col];

    #pragma unroll
    for (int i = 0; i < 4; ++i) {
        #pragma unroll
        for (int r = 0; r < 4; ++r) {
            float b1 = 3.4e38f, b2 = 3.4e38f;
            int i1 = 0x7fffffff;
            #pragma unroll
            for (int j = 0; j < 4; ++j) {
                float s = ce_j[j] - 2.0f * acc[i][j][r];
                int n = nb * 128 + wn * 64 + j * 16 + col;
                if (s < b1) { b2 = b1; b1 = s; i1 = n; }
                else if (s < b2) { b2 = s; }
            }
            #pragma unroll
            for (int m = 1; m < 16; m <<= 1) {
                float ob1 = __shfl_xor(b1, m, 16);
                float ob2 = __shfl_xor(b2, m, 16);
                int   oi  = __shfl_xor(i1, m, 16);
                bool take = (ob1 < b1) || (ob1 == b1 && oi < i1);
                float nb2 = take ? fminf(b1, ob2) : fminf(b2, ob1);
                if (take) { b1 = ob1; i1 = oi; }
                b2 = nb2;
            }
            if (col == i * 4 + r) {   // unique writer lane per (q,i,r)
                int mrow = mb * 128 + wm * 64 + i * 16 + q * 4 + r;
                float4 p;
                p.x = b1; p.y = b2; p.z = __int_as_float(i1); p.w = 0.0f;
                part[(size_t)mrow * 64 + nb * 2 + wn] = p;
            }
        }
    }
}

// ---- merge 64 column-chunk partials per row; flag near-ties ----
__global__ __launch_bounds__(256) void argmin_reduce_kernel(
        const float4* __restrict__ part,
        int* __restrict__ tokIdx,
        int* __restrict__ flist,
        int* __restrict__ flagCount) {
    int row = blockIdx.x * 4 + (threadIdx.x >> 6);
    int lane = threadIdx.x & 63;
    float4 p = part[(size_t)row * 64 + lane];
    float b1 = p.x, b2 = p.y;
    int i1 = __float_as_int(p.z);
    #pragma unroll
    for (int m = 1; m < 64; m <<= 1) {
        float ob1 = __shfl_xor(b1, m);
        float ob2 = __shfl_xor(b2, m);
        int   oi  = __shfl_xor(i1, m);
        bool take = (ob1 < b1) || (ob1 == b1 && oi < i1);
        float nb2 = take ? fminf(b1, ob2) : fminf(b2, ob1);
        if (take) { b1 = ob1; i1 = oi; }
        b2 = nb2;
    }
    if (lane == 0) {
        tokIdx[row] = i1;
        if (b2 - b1 < 0.0625f) {   // near-tie vs fp16-split noise (~6e-3): refine
            int slot = atomicAdd(flagCount, 1);
            flist[slot] = row;
        }
    }
}

// ---- fp64 exact re-resolution of flagged tokens ----
__global__ __launch_bounds__(256) void refine_kernel(const float* __restrict__ xg,
                                                     const float* __restrict__ cb,
                                                     int* __restrict__ tokIdx,
                                                     const int* __restrict__ flagList,
                                                     const int* __restrict__ flagCount) {
    __shared__ double xs[256];
    __shared__ double rb[256];
    __shared__ int    ri[256];
    int nf = *flagCount;
    for (int f = blockIdx.x; f < nf; f += gridDim.x) {
        int tok = flagList[f];
        __syncthreads();
        xs[threadIdx.x] = (double)xg[(size_t)tok * DDIM + threadIdx.x];
        __syncthreads();
        double best = 1e300;
        int bi = 0x7fffffff;
        for (int kk = 0; kk < KEMB / 256; ++kk) {
            int k = kk * 256 + threadIdx.x;
            const float* e = cb + (size_t)k * DDIM;
            double s = 0.0;
            for (int d4 = 0; d4 < DDIM / 4; ++d4) {
                float4 e4 = *(const float4*)(e + d4 * 4);
                double e0 = (double)e4.x, e1 = (double)e4.y;
                double e2 = (double)e4.z, e3 = (double)e4.w;
                s += e0 * (e0 - 2.0 * xs[d4 * 4 + 0]) + e1 * (e1 - 2.0 * xs[d4 * 4 + 1])
                   + e2 * (e2 - 2.0 * xs[d4 * 4 + 2]) + e3 * (e3 - 2.0 * xs[d4 * 4 + 3]);
            }
            if (s < best) { best = s; bi = k; }
        }
        rb[threadIdx.x] = best;
        ri[threadIdx.x] = bi;
        __syncthreads();
        if (threadIdx.x == 0) {
            double b = rb[0]; int i1 = ri[0];
            for (int c = 1; c < 256; ++c) {
                if (rb[c] < b || (rb[c] == b && ri[c] < i1)) { b = rb[c]; i1 = ri[c]; }
            }
            tokIdx[tok] = i1;
        }
        __syncthreads();
    }
}

// ---- CSR pass 1: slot assignment + integer counts (32k small atomics) ----
__global__ __launch_bounds__(256) void tokslot_kernel(const int* __restrict__ tokIdx,
                                                      int* __restrict__ countsI,
                                                      int* __restrict__ slotOf) {
    int t = blockIdx.x * 256 + threadIdx.x;
    int k = tokIdx[t];
    slotOf[t] = atomicAdd(countsI + k, 1);
}

// ---- CSR pass 2: exclusive scan of countsI[4096] -> offs ----
__global__ __launch_bounds__(256) void scan_kernel(const int* __restrict__ countsI,
                                                   int* __restrict__ offs) {
    __shared__ int part[256];
    __shared__ int pref[257];
    int tid = threadIdx.x;
    int local[16];
    int s = 0;
    #pragma unroll
    for (int i = 0; i < 16; ++i) { local[i] = countsI[tid * 16 + i]; s += local[i]; }
    part[tid] = s;
    __syncthreads();
    if (tid == 0) {
        pref[0] = 0;
        for (int i = 0; i < 256; ++i) pref[i + 1] = pref[i] + part[i];
    }
    __syncthreads();
    int run = pref[tid];
    #pragma unroll
    for (int i = 0; i < 16; ++i) { offs[tid * 16 + i] = run; run += local[i]; }
}

// ---- CSR pass 3: fill token list (no atomics) ----
__global__ __launch_bounds__(256) void filllist_kernel(const int* __restrict__ tokIdx,
                                                       const int* __restrict__ offs,
                                                       const int* __restrict__ slotOf,
                                                       int* __restrict__ tlist) {
    int t = blockIdx.x * 256 + threadIdx.x;
    int k = tokIdx[t];
    tlist[offs[k] + slotOf[t]] = t;
}

// ---- cs_pre = ema_cs*decay + (1-decay)*counts ; n = sum(cs_pre) ----
__global__ __launch_bounds__(256) void cs_kernel(const float* __restrict__ ema_cs,
                                                 const int* __restrict__ countsI,
                                                 float* __restrict__ cs_pre,
                                                 float* __restrict__ nptr) {
    int k = blockIdx.x * 256 + threadIdx.x;
    float c = ema_cs[k] * DECAYF + (1.0f - DECAYF) * (float)countsI[k];
    cs_pre[k] = c;
    float s = c;
    #pragma unroll
    for (int o = 32; o > 0; o >>= 1) s += __shfl_down(s, o);
    __shared__ float red[4];
    int lane = threadIdx.x & 63, w = threadIdx.x >> 6;
    if (lane == 0) red[w] = s;
    __syncthreads();
    if (threadIdx.x == 0) atomicAdd(nptr, red[0] + red[1] + red[2] + red[3]);
}

// ---- per-token scatter: full one-hot row + quantized row (pure streaming) ----
__global__ __launch_bounds__(256) void scatter_kernel(const float* __restrict__ cb,
                                                      const int* __restrict__ tokIdx,
                                                      float* __restrict__ quant,
                                                      float* __restrict__ enc) {
    int tok = blockIdx.x;
    int tid = threadIdx.x;
    int k = tokIdx[tok];
    float4* er = (float4*)(enc + (size_t)tok * KEMB);
    int kf4 = k >> 2, kc = k & 3;
    #pragma unroll
    for (int v = 0; v < 4; ++v) {
        int f4 = v * 256 + tid;
        float4 val = {0.f, 0.f, 0.f, 0.f};
        if (f4 == kf4) ((float*)&val)[kc] = 1.0f;
        er[f4] = val;
    }
    if (tid < 64) {
        float4 e = *(const float4*)(cb + (size_t)k * DDIM + tid * 4);
        *(float4*)(quant + (size_t)tok * DDIM + tid * 4) = e;
    }
}

// ---- balanced segmented dw reduction over the CSR list.
// 1024 blocks x 256 thr; block owns 32 consecutive slots; thread = column.
// tlist is cluster-sorted, so segments are contiguous: accumulate until the
// cluster id changes, then one atomicAdd per column. Work is skew-proof.
#define SEG_CHUNK 32
__global__ __launch_bounds__(256) void segdw_kernel(const float* __restrict__ xg,
                                                    const int* __restrict__ tlist,
                                                    const int* __restrict__ tokIdx,
                                                    float* __restrict__ dw) {
    int tid = threadIdx.x;
    int s0 = blockIdx.x * SEG_CHUNK;
    float acc = 0.0f;
    int curk = -1;
    for (int s = s0; s < s0 + SEG_CHUNK; ++s) {
        int t = tlist[s];
        int k = tokIdx[t];
        if (k != curk) {
            if (curk >= 0) atomicAdd(dw + (size_t)curk * DDIM + tid, acc);
            acc = 0.0f;
            curk = k;
        }
        acc += xg[(size_t)t * DDIM + tid];
    }
    if (curk >= 0) atomicAdd(dw + (size_t)curk * DDIM + tid, acc);
}

// ---- epilogue: new_ema_w, laplace-smoothed cs, new_codebook ----
__global__ __launch_bounds__(256) void epi_kernel(const float* __restrict__ ema_w,
                                                  const float* __restrict__ dw,
                                                  const float* __restrict__ cs_pre,
                                                  const float* __restrict__ nptr,
                                                  float* __restrict__ new_cb,
                                                  float* __restrict__ new_w,
                                                  float* __restrict__ cs_out) {
    int gid = blockIdx.x * 256 + threadIdx.x;   // 0 .. 1048575
    int k = gid >> 8, d = gid & 255;
    float n = *nptr;
    float csp = cs_pre[k];
    float cs = (csp + EPSF) / (n + (float)KEMB * EPSF) * n;
    float w = ema_w[gid] * DECAYF + (1.0f - DECAYF) * dw[gid];
    new_w[gid] = w;
    new_cb[gid] = w / cs;
    if (d == 0) cs_out[k] = cs;
}

extern "C" void kernel_launch(void* const* d_in, const int* in_sizes, int n_in,
                              void* d_out, int out_size, void* d_ws, size_t ws_size,
                              hipStream_t stream) {
    const float* xg     = (const float*)d_in[0];   // [32768,256]
    const float* cbg    = (const float*)d_in[1];   // [4096,256]
    const float* ema_w  = (const float*)d_in[2];   // [4096,256]
    const float* ema_cs = (const float*)d_in[3];   // [4096]

    float* out = (float*)d_out;
    unsigned char* wsb = (unsigned char*)d_ws;

    float* quant  = out + OFF_Q;
    float* enc    = out + OFF_E;
    float* new_cb = out + OFF_CB;
    float* new_w  = out + OFF_W;
    float* cs_out = out + OFF_CS;

    _Float16* Ahat = (_Float16*)(wsb + B_AHAT);
    _Float16* Bhat = (_Float16*)(wsb + B_BHAT);
    float4* part   = (float4*)(wsb + B_PART);
    float* ce      = (float*)(wsb + B_CE);
    int*   countsI = (int*)(wsb + B_CNTI);
    float* cs_pre  = (float*)(wsb + B_CSP);
    int*   offs    = (int*)(wsb + B_OFFS);
    float* nptr    = (float*)(wsb + B_NPTR);
    int*   flagCnt = (int*)(wsb + B_NPTR + 4);
    int*   tokIdx  = (int*)(wsb + B_TIDX);
    int*   flist   = (int*)(wsb + B_FLIST);
    int*   slotOf  = (int*)(wsb + B_SLOT);
    int*   tlist   = (int*)(wsb + B_TLIST);
    float* dw      = (float*)(wsb + B_DW);

    // zero-init (d_out / d_ws are poisoned with 0xAA before every call).
    hipMemsetAsync(countsI, 0, KEMB * sizeof(int), stream);
    hipMemsetAsync(nptr, 0, 8, stream);                        // n + flagCount
    hipMemsetAsync(dw, 0, (size_t)KEMB * DDIM * sizeof(float), stream);

    splitA_kernel<<<(NTOK * 32) / 256, 256, 0, stream>>>(xg, Ahat);
    splitB_kernel<<<(KEMB * 32) / 256, 256, 0, stream>>>(cbg, Bhat, ce);
    gemm_argmin_kernel<<<dim3(KEMB / 128, NTOK / 128), 256, 0, stream>>>(Ahat, Bhat, ce, part);
    argmin_reduce_kernel<<<NTOK / 4, 256, 0, stream>>>(part, tokIdx, flist, flagCnt);
    refine_kernel<<<256, 256, 0, stream>>>(xg, cbg, tokIdx, flist, flagCnt);
    tokslot_kernel<<<NTOK / 256, 256, 0, stream>>>(tokIdx, countsI, slotOf);
    cs_kernel<<<KEMB / 256, 256, 0, stream>>>(ema_cs, countsI, cs_pre, nptr);
    scan_kernel<<<1, 256, 0, stream>>>(countsI, offs);
    filllist_kernel<<<NTOK / 256, 256, 0, stream>>>(tokIdx, offs, slotOf, tlist);
    scatter_kernel<<<NTOK, 256, 0, stream>>>(cbg, tokIdx, quant, enc);
    segdw_kernel<<<NTOK / SEG_CHUNK, 256, 0, stream>>>(xg, tlist, tokIdx, dw);
    epi_kernel<<<(KEMB * DDIM) / 256, 256, 0, stream>>>(ema_w, dw, cs_pre, nptr,
                                                        new_cb, new_w, cs_out);
}

// Round 7
// 1030.084 us; speedup vs baseline: 1.3636x; 1.0021x over previous
//
#include <hip/hip_runtime.h>
#include <hip/hip_bf16.h>

#define NTOK 32768
#define KEMB 4096
#define DDIM 256
#define DECAYF 0.99f
#define EPSF 1e-5f
#define KSPLIT 512   // 2-term fp16 split: [Xh|Xl] . [Ch|Ch]

// ---------------- workspace layout (BYTE offsets) ----------------
#define B_AHAT  0ull          // 32768*512 f16 = 33554432 B  swizzled [Xh|Xl]
#define B_BHAT  33554432ull   // 4096*512 f16  = 4194304 B   swizzled [Ch|Ch]
#define B_PART  37748736ull   // 32768*64 float4 = 33554432 B per-64col-chunk (b1,b2,idx)
#define B_CE    71303168ull   // 4096 f32
#define B_CNTI  71319552ull   // 4096 int: integer counts (atomic slot counters)
#define B_CSP   71335936ull   // 4096 f32: cs_pre
#define B_OFFS  71352320ull   // 4096 int: CSR offsets
#define B_NPTR  71368704ull   // f32 n ; +4 int flagCount
#define B_TIDX  71368768ull   // 32768 int: per-token argmin
#define B_FLIST 71499840ull   // 32768 int: flagged tokens
#define B_SLOT  71630912ull   // 32768 int: slot of token within its cluster
#define B_TLIST 71761984ull   // 32768 int: CSR token list
#define B_DW    71893056ull   // 4096*256 f32 = 4194304 B segment sums
// total ~76.1 MB

// ---------------- output layout (float offsets) ----------------
#define OFF_Q  0ull                 // quantized  [32768,256]
#define OFF_E  8388608ull           // encodings  [32768,4096]
#define OFF_CB 142606336ull         // new_codebook [4096,256]
#define OFF_W  143654912ull         // new_ema_w    [4096,256]
#define OFF_CS 144703488ull         // cs [4096]

typedef __attribute__((ext_vector_type(8))) _Float16 f16x8;
typedef __attribute__((ext_vector_type(4))) float f32x4;

// ---- MFMA-swizzled split: flat idx (((g*16+s)*4+q)*16+m16)*8+j.
// g = row/16, s = 32-k step, q = 8-chunk within step, m16 = row%16.
// chunk c = s*4+q in [0,64): c<32 -> hi(fp16) of d-chunk c, c>=32 -> lo of c-32.
// A wave's fragment load becomes Ap[((g*16+s)<<6)+lane]: 1KB coalesced.
__global__ __launch_bounds__(256) void splitAswz_kernel(const float* __restrict__ x,
                                                        _Float16* __restrict__ Ahat) {
    int gid = blockIdx.x * 256 + threadIdx.x;   // 0 .. 32768*64-1
    int m16 = gid & 15;
    int c   = (gid >> 4) & 63;
    int g   = gid >> 10;
    int row = g * 16 + m16;
    int dchunk = c & 31;
    const float* xp = x + (size_t)row * DDIM + dchunk * 8;
    f16x8 v;
    if (c < 32) {
        #pragma unroll
        for (int t = 0; t < 8; ++t) v[t] = (_Float16)xp[t];
    } else {
        #pragma unroll
        for (int t = 0; t < 8; ++t) {
            float f = xp[t];
            _Float16 h = (_Float16)f;
            v[t] = (_Float16)(f - (float)h);
        }
    }
    *(f16x8*)(Ahat + (size_t)gid * 8) = v;   // fully coalesced
}

// ---- B: both halves are hi (codebook is NOT split; [Ch|Ch]) ----
__global__ __launch_bounds__(256) void splitBswz_kernel(const float* __restrict__ cb,
                                                        _Float16* __restrict__ Bhat) {
    int gid = blockIdx.x * 256 + threadIdx.x;   // 0 .. 4096*64-1
    int m16 = gid & 15;
    int c   = (gid >> 4) & 63;
    int g   = gid >> 10;
    int row = g * 16 + m16;
    int dchunk = c & 31;
    const float* cp = cb + (size_t)row * DDIM + dchunk * 8;
    f16x8 v;
    #pragma unroll
    for (int t = 0; t < 8; ++t) v[t] = (_Float16)cp[t];
    *(f16x8*)(Bhat + (size_t)gid * 8) = v;
}

// ---- per-cluster squared norms (fp32), one wave per cluster row ----
__global__ __launch_bounds__(256) void ce_kernel(const float* __restrict__ cb,
                                                 float* __restrict__ ce) {
    int k = blockIdx.x * 4 + (threadIdx.x >> 6);
    int lane = threadIdx.x & 63;
    float4 v = *(const float4*)(cb + (size_t)k * DDIM + lane * 4);
    float s = v.x * v.x + v.y * v.y + v.z * v.z + v.w * v.w;
    #pragma unroll
    for (int o = 32; o > 0; o >>= 1) s += __shfl_down(s, o);
    if (lane == 0) ce[k] = s;
}

// ---- LDS-free fp16 MFMA GEMM (M=32768, N=4096, K=512) + fused argmin.
// Fragments load straight from the swizzled global layout: one coalesced
// 1KB global_load_dwordx4 per fragment. No LDS, no __syncthreads.
// Grid: x = nb (fast) so 32 consecutive blocks share one A-tile (L2-hot).
__global__ __launch_bounds__(256) void gemm_argmin_kernel(
        const _Float16* __restrict__ Ahat,
        const _Float16* __restrict__ Bhat,
        const float* __restrict__ ceg,
        float4* __restrict__ part) {
    const int tid  = threadIdx.x;
    const int lane = tid & 63;
    const int wave = tid >> 6;
    const int wm = wave >> 1, wn = wave & 1;  // 2x2 wave grid, 64x64 per wave
    const int nb = blockIdx.x, mb = blockIdx.y;
    const int col = lane & 15, q = lane >> 4;

    const f16x8* Ap = (const f16x8*)Ahat;
    const f16x8* Bp = (const f16x8*)Bhat;
    const int gA0 = mb * 8 + wm * 4;   // first 16-row group of this wave's A
    const int gB0 = nb * 8 + wn * 4;   // first 16-col group of this wave's B

    f32x4 zero = {0.f, 0.f, 0.f, 0.f};
    f32x4 acc[4][4];
    #pragma unroll
    for (int i = 0; i < 4; ++i)
        #pragma unroll
        for (int j = 0; j < 4; ++j) acc[i][j] = zero;

    #pragma unroll 2
    for (int s = 0; s < KSPLIT / 32; ++s) {
        f16x8 a[4], b[4];
        #pragma unroll
        for (int i = 0; i < 4; ++i)
            a[i] = Ap[(((size_t)(gA0 + i) * 16 + s) << 6) + lane];
        #pragma unroll
        for (int j = 0; j < 4; ++j)
            b[j] = Bp[(((size_t)(gB0 + j) * 16 + s) << 6) + lane];
        #pragma unroll
        for (int i = 0; i < 4; ++i)
            #pragma unroll
            for (int j = 0; j < 4; ++j)
                acc[i][j] = __builtin_amdgcn_mfma_f32_16x16x32_f16(a[i], b[j], acc[i][j], 0, 0, 0);
    }

    // epilogue: s = ||c||^2 - 2*dot. C/D layout: col = lane&15, row = q*4+reg.
    float ce_j[4];
    #pragma unroll
    for (int j = 0; j < 4; ++j) ce_j[j] = ceg[nb * 128 + wn * 64 + j * 16 + col];

    #pragma unroll
    for (int i = 0; i < 4; ++i) {
        #pragma unroll
        for (int r = 0; r < 4; ++r) {
            float b1 = 3.4e38f, b2 = 3.4e38f;
            int i1 = 0x7fffffff;
            #pragma unroll
            for (int j = 0; j < 4; ++j) {
                float s = ce_j[j] - 2.0f * acc[i][j][r];
                int n = nb * 128 + wn * 64 + j * 16 + col;
                if (s < b1) { b2 = b1; b1 = s; i1 = n; }
                else if (s < b2) { b2 = s; }
            }
            #pragma unroll
            for (int m = 1; m < 16; m <<= 1) {
                float ob1 = __shfl_xor(b1, m, 16);
                float ob2 = __shfl_xor(b2, m, 16);
                int   oi  = __shfl_xor(i1, m, 16);
                bool take = (ob1 < b1) || (ob1 == b1 && oi < i1);
                float nb2 = take ? fminf(b1, ob2) : fminf(b2, ob1);
                if (take) { b1 = ob1; i1 = oi; }
                b2 = nb2;
            }
            if (col == i * 4 + r) {   // unique writer lane per (q,i,r)
                int mrow = mb * 128 + wm * 64 + i * 16 + q * 4 + r;
                float4 p;
                p.x = b1; p.y = b2; p.z = __int_as_float(i1); p.w = 0.0f;
                part[(size_t)mrow * 64 + nb * 2 + wn] = p;
            }
        }
    }
}

// ---- merge 64 column-chunk partials per row; flag near-ties ----
__global__ __launch_bounds__(256) void argmin_reduce_kernel(
        const float4* __restrict__ part,
        int* __restrict__ tokIdx,
        int* __restrict__ flist,
        int* __restrict__ flagCount) {
    int row = blockIdx.x * 4 + (threadIdx.x >> 6);
    int lane = threadIdx.x & 63;
    float4 p = part[(size_t)row * 64 + lane];
    float b1 = p.x, b2 = p.y;
    int i1 = __float_as_int(p.z);
    #pragma unroll
    for (int m = 1; m < 64; m <<= 1) {
        float ob1 = __shfl_xor(b1, m);
        float ob2 = __shfl_xor(b2, m);
        int   oi  = __shfl_xor(i1, m);
        bool take = (ob1 < b1) || (ob1 == b1 && oi < i1);
        float nb2 = take ? fminf(b1, ob2) : fminf(b2, ob1);
        if (take) { b1 = ob1; i1 = oi; }
        b2 = nb2;
    }
    if (lane == 0) {
        tokIdx[row] = i1;
        if (b2 - b1 < 0.0625f) {   // near-tie vs fp16-split noise (~6e-3): refine
            int slot = atomicAdd(flagCount, 1);
            flist[slot] = row;
        }
    }
}

// ---- fp64 exact re-resolution of flagged tokens ----
__global__ __launch_bounds__(256) void refine_kernel(const float* __restrict__ xg,
                                                     const float* __restrict__ cb,
                                                     int* __restrict__ tokIdx,
                                                     const int* __restrict__ flagList,
                                                     const int* __restrict__ flagCount) {
    __shared__ double xs[256];
    __shared__ double rb[256];
    __shared__ int    ri[256];
    int nf = *flagCount;
    for (int f = blockIdx.x; f < nf; f += gridDim.x) {
        int tok = flagList[f];
        __syncthreads();
        xs[threadIdx.x] = (double)xg[(size_t)tok * DDIM + threadIdx.x];
        __syncthreads();
        double best = 1e300;
        int bi = 0x7fffffff;
        for (int kk = 0; kk < KEMB / 256; ++kk) {
            int k = kk * 256 + threadIdx.x;
            const float* e = cb + (size_t)k * DDIM;
            double s = 0.0;
            for (int d4 = 0; d4 < DDIM / 4; ++d4) {
                float4 e4 = *(const float4*)(e + d4 * 4);
                double e0 = (double)e4.x, e1 = (double)e4.y;
                double e2 = (double)e4.z, e3 = (double)e4.w;
                s += e0 * (e0 - 2.0 * xs[d4 * 4 + 0]) + e1 * (e1 - 2.0 * xs[d4 * 4 + 1])
                   + e2 * (e2 - 2.0 * xs[d4 * 4 + 2]) + e3 * (e3 - 2.0 * xs[d4 * 4 + 3]);
            }
            if (s < best) { best = s; bi = k; }
        }
        rb[threadIdx.x] = best;
        ri[threadIdx.x] = bi;
        __syncthreads();
        if (threadIdx.x == 0) {
            double b = rb[0]; int i1 = ri[0];
            for (int c = 1; c < 256; ++c) {
                if (rb[c] < b || (rb[c] == b && ri[c] < i1)) { b = rb[c]; i1 = ri[c]; }
            }
            tokIdx[tok] = i1;
        }
        __syncthreads();
    }
}

// ---- CSR pass 1: slot assignment + integer counts (32k small atomics) ----
__global__ __launch_bounds__(256) void tokslot_kernel(const int* __restrict__ tokIdx,
                                                      int* __restrict__ countsI,
                                                      int* __restrict__ slotOf) {
    int t = blockIdx.x * 256 + threadIdx.x;
    int k = tokIdx[t];
    slotOf[t] = atomicAdd(countsI + k, 1);
}

// ---- CSR pass 2: exclusive scan of countsI[4096] -> offs ----
__global__ __launch_bounds__(256) void scan_kernel(const int* __restrict__ countsI,
                                                   int* __restrict__ offs) {
    __shared__ int part[256];
    __shared__ int pref[257];
    int tid = threadIdx.x;
    int local[16];
    int s = 0;
    #pragma unroll
    for (int i = 0; i < 16; ++i) { local[i] = countsI[tid * 16 + i]; s += local[i]; }
    part[tid] = s;
    __syncthreads();
    if (tid == 0) {
        pref[0] = 0;
        for (int i = 0; i < 256; ++i) pref[i + 1] = pref[i] + part[i];
    }
    __syncthreads();
    int run = pref[tid];
    #pragma unroll
    for (int i = 0; i < 16; ++i) { offs[tid * 16 + i] = run; run += local[i]; }
}

// ---- CSR pass 3: fill token list (no atomics) ----
__global__ __launch_bounds__(256) void filllist_kernel(const int* __restrict__ tokIdx,
                                                       const int* __restrict__ offs,
                                                       const int* __restrict__ slotOf,
                                                       int* __restrict__ tlist) {
    int t = blockIdx.x * 256 + threadIdx.x;
    int k = tokIdx[t];
    tlist[offs[k] + slotOf[t]] = t;
}

// ---- cs_pre = ema_cs*decay + (1-decay)*counts ; n = sum(cs_pre) ----
__global__ __launch_bounds__(256) void cs_kernel(const float* __restrict__ ema_cs,
                                                 const int* __restrict__ countsI,
                                                 float* __restrict__ cs_pre,
                                                 float* __restrict__ nptr) {
    int k = blockIdx.x * 256 + threadIdx.x;
    float c = ema_cs[k] * DECAYF + (1.0f - DECAYF) * (float)countsI[k];
    cs_pre[k] = c;
    float s = c;
    #pragma unroll
    for (int o = 32; o > 0; o >>= 1) s += __shfl_down(s, o);
    __shared__ float red[4];
    int lane = threadIdx.x & 63, w = threadIdx.x >> 6;
    if (lane == 0) red[w] = s;
    __syncthreads();
    if (threadIdx.x == 0) atomicAdd(nptr, red[0] + red[1] + red[2] + red[3]);
}

// ---- per-token scatter: full one-hot row + quantized row (pure streaming) ----
__global__ __launch_bounds__(256) void scatter_kernel(const float* __restrict__ cb,
                                                      const int* __restrict__ tokIdx,
                                                      float* __restrict__ quant,
                                                      float* __restrict__ enc) {
    int tok = blockIdx.x;
    int tid = threadIdx.x;
    int k = tokIdx[tok];
    float4* er = (float4*)(enc + (size_t)tok * KEMB);
    int kf4 = k >> 2, kc = k & 3;
    #pragma unroll
    for (int v = 0; v < 4; ++v) {
        int f4 = v * 256 + tid;
        float4 val = {0.f, 0.f, 0.f, 0.f};
        if (f4 == kf4) ((float*)&val)[kc] = 1.0f;
        er[f4] = val;
    }
    if (tid < 64) {
        float4 e = *(const float4*)(cb + (size_t)k * DDIM + tid * 4);
        *(float4*)(quant + (size_t)tok * DDIM + tid * 4) = e;
    }
}

// ---- balanced segmented dw reduction over the CSR list ----
#define SEG_CHUNK 32
__global__ __launch_bounds__(256) void segdw_kernel(const float* __restrict__ xg,
                                                    const int* __restrict__ tlist,
                                                    const int* __restrict__ tokIdx,
                                                    float* __restrict__ dw) {
    int tid = threadIdx.x;
    int s0 = blockIdx.x * SEG_CHUNK;
    float acc = 0.0f;
    int curk = -1;
    for (int s = s0; s < s0 + SEG_CHUNK; ++s) {
        int t = tlist[s];
        int k = tokIdx[t];
        if (k != curk) {
            if (curk >= 0) atomicAdd(dw + (size_t)curk * DDIM + tid, acc);
            acc = 0.0f;
            curk = k;
        }
        acc += xg[(size_t)t * DDIM + tid];
    }
    if (curk >= 0) atomicAdd(dw + (size_t)curk * DDIM + tid, acc);
}

// ---- epilogue: new_ema_w, laplace-smoothed cs, new_codebook ----
__global__ __launch_bounds__(256) void epi_kernel(const float* __restrict__ ema_w,
                                                  const float* __restrict__ dw,
                                                  const float* __restrict__ cs_pre,
                                                  const float* __restrict__ nptr,
                                                  float* __restrict__ new_cb,
                                                  float* __restrict__ new_w,
                                                  float* __restrict__ cs_out) {
    int gid = blockIdx.x * 256 + threadIdx.x;   // 0 .. 1048575
    int k = gid >> 8, d = gid & 255;
    float n = *nptr;
    float csp = cs_pre[k];
    float cs = (csp + EPSF) / (n + (float)KEMB * EPSF) * n;
    float w = ema_w[gid] * DECAYF + (1.0f - DECAYF) * dw[gid];
    new_w[gid] = w;
    new_cb[gid] = w / cs;
    if (d == 0) cs_out[k] = cs;
}

extern "C" void kernel_launch(void* const* d_in, const int* in_sizes, int n_in,
                              void* d_out, int out_size, void* d_ws, size_t ws_size,
                              hipStream_t stream) {
    const float* xg     = (const float*)d_in[0];   // [32768,256]
    const float* cbg    = (const float*)d_in[1];   // [4096,256]
    const float* ema_w  = (const float*)d_in[2];   // [4096,256]
    const float* ema_cs = (const float*)d_in[3];   // [4096]

    float* out = (float*)d_out;
    unsigned char* wsb = (unsigned char*)d_ws;

    float* quant  = out + OFF_Q;
    float* enc    = out + OFF_E;
    float* new_cb = out + OFF_CB;
    float* new_w  = out + OFF_W;
    float* cs_out = out + OFF_CS;

    _Float16* Ahat = (_Float16*)(wsb + B_AHAT);
    _Float16* Bhat = (_Float16*)(wsb + B_BHAT);
    float4* part   = (float4*)(wsb + B_PART);
    float* ce      = (float*)(wsb + B_CE);
    int*   countsI = (int*)(wsb + B_CNTI);
    float* cs_pre  = (float*)(wsb + B_CSP);
    int*   offs    = (int*)(wsb + B_OFFS);
    float* nptr    = (float*)(wsb + B_NPTR);
    int*   flagCnt = (int*)(wsb + B_NPTR + 4);
    int*   tokIdx  = (int*)(wsb + B_TIDX);
    int*   flist   = (int*)(wsb + B_FLIST);
    int*   slotOf  = (int*)(wsb + B_SLOT);
    int*   tlist   = (int*)(wsb + B_TLIST);
    float* dw      = (float*)(wsb + B_DW);

    // zero-init (d_out / d_ws are poisoned with 0xAA before every call).
    hipMemsetAsync(countsI, 0, KEMB * sizeof(int), stream);
    hipMemsetAsync(nptr, 0, 8, stream);                        // n + flagCount
    hipMemsetAsync(dw, 0, (size_t)KEMB * DDIM * sizeof(float), stream);

    splitAswz_kernel<<<(NTOK * 64) / 256, 256, 0, stream>>>(xg, Ahat);
    splitBswz_kernel<<<(KEMB * 64) / 256, 256, 0, stream>>>(cbg, Bhat);
    ce_kernel<<<KEMB / 4, 256, 0, stream>>>(cbg, ce);
    gemm_argmin_kernel<<<dim3(KEMB / 128, NTOK / 128), 256, 0, stream>>>(Ahat, Bhat, ce, part);
    argmin_reduce_kernel<<<NTOK / 4, 256, 0, stream>>>(part, tokIdx, flist, flagCnt);
    refine_kernel<<<256, 256, 0, stream>>>(xg, cbg, tokIdx, flist, flagCnt);
    tokslot_kernel<<<NTOK / 256, 256, 0, stream>>>(tokIdx, countsI, slotOf);
    cs_kernel<<<KEMB / 256, 256, 0, stream>>>(ema_cs, countsI, cs_pre, nptr);
    scan_kernel<<<1, 256, 0, stream>>>(countsI, offs);
    filllist_kernel<<<NTOK / 256, 256, 0, stream>>>(tokIdx, offs, slotOf, tlist);
    scatter_kernel<<<NTOK, 256, 0, stream>>>(cbg, tokIdx, quant, enc);
    segdw_kernel<<<NTOK / SEG_CHUNK, 256, 0, stream>>>(xg, tlist, tokIdx, dw);
    epi_kernel<<<(KEMB * DDIM) / 256, 256, 0, stream>>>(ema_w, dw, cs_pre, nptr,
                                                        new_cb, new_w, cs_out);
}

// Round 8
// 861.483 us; speedup vs baseline: 1.6305x; 1.1957x over previous
//
#include <hip/hip_runtime.h>
#include <hip/hip_bf16.h>

#define NTOK 32768
#define KEMB 4096
#define DDIM 256
#define DECAYF 0.99f
#define EPSF 1e-5f
#define KSPLIT 256          // hi-only fp16: Xh . Ch, error handled by flag+refine
#define FLAG_THETA 0.09f    // ~5 sigma of hi-only distance-diff noise (0.018)
#define PRUNE_MARGIN 0.25f  // 2*theta + 6*sigma error bound for chunk pruning

// ---------------- workspace layout (BYTE offsets) ----------------
#define B_AHAT  0ull          // 32768*256 f16 = 16777216 B  Xh
#define B_BHAT  16777216ull   // 4096*256 f16  = 2097152 B   Ch
#define B_PART  18874368ull   // 32768*64 float4 = 33554432 B per-64col-chunk (b1,b2,idx)
#define B_CE    52428800ull   // 4096 f32
#define B_CNTI  52445184ull   // 4096 int: integer counts (atomic slot counters)
#define B_CSP   52461568ull   // 4096 f32: cs_pre
#define B_OFFS  52477952ull   // 4096 int: CSR offsets
#define B_NPTR  52494336ull   // f32 n ; +4 int flagCount
#define B_TIDX  52494400ull   // 32768 int: per-token argmin
#define B_FLIST 52625472ull   // 32768 int: flagged tokens
#define B_SLOT  52756544ull   // 32768 int: slot of token within its cluster
#define B_TLIST 52887616ull   // 32768 int: CSR token list
#define B_DW    53018688ull   // 4096*256 f32 = 4194304 B segment sums
// total ~57.2 MB

// ---------------- output layout (float offsets) ----------------
#define OFF_Q  0ull                 // quantized  [32768,256]
#define OFF_E  8388608ull           // encodings  [32768,4096]
#define OFF_CB 142606336ull         // new_codebook [4096,256]
#define OFF_W  143654912ull         // new_ema_w    [4096,256]
#define OFF_CS 144703488ull         // cs [4096]

typedef __attribute__((ext_vector_type(8))) _Float16 f16x8;
typedef __attribute__((ext_vector_type(4))) float f32x4;

// ---- plain coalesced fp32 -> fp16 cast (used for both X and codebook) ----
__global__ __launch_bounds__(256) void cast16_kernel(const float* __restrict__ src,
                                                     _Float16* __restrict__ dst) {
    size_t gid = (size_t)blockIdx.x * 256 + threadIdx.x;
    const float* sp = src + gid * 8;
    f16x8 v;
    #pragma unroll
    for (int t = 0; t < 8; ++t) v[t] = (_Float16)sp[t];
    *(f16x8*)(dst + gid * 8) = v;
}

// ---- per-cluster squared norms (fp32), one wave per cluster row ----
__global__ __launch_bounds__(256) void ce_kernel(const float* __restrict__ cb,
                                                 float* __restrict__ ce) {
    int k = blockIdx.x * 4 + (threadIdx.x >> 6);
    int lane = threadIdx.x & 63;
    float4 v = *(const float4*)(cb + (size_t)k * DDIM + lane * 4);
    float s = v.x * v.x + v.y * v.y + v.z * v.z + v.w * v.w;
    #pragma unroll
    for (int o = 32; o > 0; o >>= 1) s += __shfl_down(s, o);
    if (lane == 0) ce[k] = s;
}

// ---- fp16 MFMA GEMM (M=32768, N=4096, K=256) with fused per-row argmin.
// R3-validated structure: 128x128 tile, BK=64, global_load_lds width-16,
// XOR-swizzled chunk staging -> conflict-free ds_read_b128.
// Grid: x = nb (fast) so 32 consecutive blocks share one A-tile (L2-hot).
__global__ __launch_bounds__(256) void gemm_argmin_kernel(
        const _Float16* __restrict__ Ahat,
        const _Float16* __restrict__ Bhat,
        const float* __restrict__ ceg,
        float4* __restrict__ part) {
    __shared__ _Float16 As[128 * 64];   // 16 KB
    __shared__ _Float16 Bs[128 * 64];   // 16 KB
    const int tid  = threadIdx.x;
    const int lane = tid & 63;
    const int wave = tid >> 6;
    const int wm = wave >> 1, wn = wave & 1;  // 2x2 wave grid, 64x64 per wave
    const int nb = blockIdx.x, mb = blockIdx.y;
    const int col = lane & 15, q = lane >> 4;
    const int cswz = q ^ (col & 7);           // reader chunk swizzle base

    const int srow = tid >> 3;
    const int sswz = (tid & 7) ^ (srow & 7);
    const _Float16* ag = Ahat + (size_t)(mb * 128 + srow) * KSPLIT + sswz * 8;
    const _Float16* bg = Bhat + (size_t)(nb * 128 + srow) * KSPLIT + sswz * 8;

    f32x4 zero = {0.f, 0.f, 0.f, 0.f};
    f32x4 acc[4][4];
    #pragma unroll
    for (int i = 0; i < 4; ++i)
        #pragma unroll
        for (int j = 0; j < 4; ++j) acc[i][j] = zero;

    for (int kt = 0; kt < KSPLIT / 64; ++kt) {
        __syncthreads();
        #pragma unroll
        for (int n = 0; n < 4; ++n) {
            __builtin_amdgcn_global_load_lds(
                (const __attribute__((address_space(1))) void*)(ag + (size_t)n * 32 * KSPLIT + kt * 64),
                (__attribute__((address_space(3))) void*)(As + n * 2048 + tid * 8), 16, 0, 0);
            __builtin_amdgcn_global_load_lds(
                (const __attribute__((address_space(1))) void*)(bg + (size_t)n * 32 * KSPLIT + kt * 64),
                (__attribute__((address_space(3))) void*)(Bs + n * 2048 + tid * 8), 16, 0, 0);
        }
        __syncthreads();

        const f16x8* Av = (const f16x8*)As;
        const f16x8* Bv = (const f16x8*)Bs;
        #pragma unroll
        for (int ks = 0; ks < 2; ++ks) {
            f16x8 a[4], b[4];
            #pragma unroll
            for (int i = 0; i < 4; ++i)
                a[i] = Av[(wm * 64 + i * 16 + col) * 8 + (cswz ^ (ks * 4))];
            #pragma unroll
            for (int j = 0; j < 4; ++j)
                b[j] = Bv[(wn * 64 + j * 16 + col) * 8 + (cswz ^ (ks * 4))];
            #pragma unroll
            for (int i = 0; i < 4; ++i)
                #pragma unroll
                for (int j = 0; j < 4; ++j)
                    acc[i][j] = __builtin_amdgcn_mfma_f32_16x16x32_f16(a[i], b[j], acc[i][j], 0, 0, 0);
        }
    }

    // epilogue: s = ||c||^2 - 2*dot. C/D layout: col = lane&15, row = q*4+reg.
    float ce_j[4];
    #pragma unroll
    for (int j = 0; j < 4; ++j) ce_j[j] = ceg[nb * 128 + wn * 64 + j * 16 + col];

    #pragma unroll
    for (int i = 0; i < 4; ++i) {
        #pragma unroll
        for (int r = 0; r < 4; ++r) {
            float b1 = 3.4e38f, b2 = 3.4e38f;
            int i1 = 0x7fffffff;
            #pragma unroll
            for (int j = 0; j < 4; ++j) {
                float s = ce_j[j] - 2.0f * acc[i][j][r];
                int n = nb * 128 + wn * 64 + j * 16 + col;
                if (s < b1) { b2 = b1; b1 = s; i1 = n; }
                else if (s < b2) { b2 = s; }
            }
            #pragma unroll
            for (int m = 1; m < 16; m <<= 1) {
                float ob1 = __shfl_xor(b1, m, 16);
                float ob2 = __shfl_xor(b2, m, 16);
                int   oi  = __shfl_xor(i1, m, 16);
                bool take = (ob1 < b1) || (ob1 == b1 && oi < i1);
                float nb2 = take ? fminf(b1, ob2) : fminf(b2, ob1);
                if (take) { b1 = ob1; i1 = oi; }
                b2 = nb2;
            }
            if (col == i * 4 + r) {   // unique writer lane per (q,i,r)
                int mrow = mb * 128 + wm * 64 + i * 16 + q * 4 + r;
                float4 p;
                p.x = b1; p.y = b2; p.z = __int_as_float(i1); p.w = 0.0f;
                part[(size_t)mrow * 64 + nb * 2 + wn] = p;
            }
        }
    }
}

// ---- merge 64 column-chunk partials per row; flag near-ties ----
__global__ __launch_bounds__(256) void argmin_reduce_kernel(
        const float4* __restrict__ part,
        int* __restrict__ tokIdx,
        int* __restrict__ flist,
        int* __restrict__ flagCount) {
    int row = blockIdx.x * 4 + (threadIdx.x >> 6);
    int lane = threadIdx.x & 63;
    float4 p = part[(size_t)row * 64 + lane];
    float b1 = p.x, b2 = p.y;
    int i1 = __float_as_int(p.z);
    #pragma unroll
    for (int m = 1; m < 64; m <<= 1) {
        float ob1 = __shfl_xor(b1, m);
        float ob2 = __shfl_xor(b2, m);
        int   oi  = __shfl_xor(i1, m);
        bool take = (ob1 < b1) || (ob1 == b1 && oi < i1);
        float nb2 = take ? fminf(b1, ob2) : fminf(b2, ob1);
        if (take) { b1 = ob1; i1 = oi; }
        b2 = nb2;
    }
    if (lane == 0) {
        tokIdx[row] = i1;
        if (b2 - b1 < FLAG_THETA) {
            int slot = atomicAdd(flagCount, 1);
            flist[slot] = row;
        }
    }
}

// ---- chunk-pruned fp64 refine: one wave per flagged token.
// part[tok*64+c].x is chunk c's approx best; chunks with p.x > b1+PRUNE_MARGIN
// provably (6-sigma bound) cannot hold the true argmin. fp64-scan survivors:
// lane = cluster within chunk, serial 256-dim fp64 dot per lane.
__global__ __launch_bounds__(256) void refine_kernel(const float* __restrict__ xg,
                                                     const float* __restrict__ cb,
                                                     const float4* __restrict__ part,
                                                     int* __restrict__ tokIdx,
                                                     const int* __restrict__ flagList,
                                                     const int* __restrict__ flagCount) {
    int nf = *flagCount;
    int lane = threadIdx.x & 63;
    int wid = (blockIdx.x * 256 + threadIdx.x) >> 6;
    int nw = (gridDim.x * 256) >> 6;
    for (int f = wid; f < nf; f += nw) {
        int tok = flagList[f];
        float cb1 = part[(size_t)tok * 64 + lane].x;
        float b1 = cb1;
        #pragma unroll
        for (int m = 1; m < 64; m <<= 1) b1 = fminf(b1, __shfl_xor(b1, m));
        unsigned long long mask = __ballot(cb1 <= b1 + PRUNE_MARGIN);
        double best = 1e300;
        int bi = 0x7fffffff;
        const float* xr = xg + (size_t)tok * DDIM;
        while (mask) {
            int c = __ffsll(mask) - 1;
            mask &= mask - 1;
            int k = c * 64 + lane;
            const float* e = cb + (size_t)k * DDIM;
            double s = 0.0;
            for (int d4 = 0; d4 < DDIM / 4; ++d4) {
                float4 e4 = *(const float4*)(e + d4 * 4);
                float4 x4 = *(const float4*)(xr + d4 * 4);
                double e0 = (double)e4.x, e1 = (double)e4.y;
                double e2 = (double)e4.z, e3 = (double)e4.w;
                s += e0 * (e0 - 2.0 * (double)x4.x) + e1 * (e1 - 2.0 * (double)x4.y)
                   + e2 * (e2 - 2.0 * (double)x4.z) + e3 * (e3 - 2.0 * (double)x4.w);
            }
            if (s < best || (s == best && k < bi)) { best = s; bi = k; }
        }
        #pragma unroll
        for (int m = 1; m < 64; m <<= 1) {
            double ob = __shfl_xor(best, m);
            int   oi  = __shfl_xor(bi, m);
            if (ob < best || (ob == best && oi < bi)) { best = ob; bi = oi; }
        }
        if (lane == 0) tokIdx[tok] = bi;
    }
}

// ---- CSR pass 1: slot assignment + integer counts (32k small atomics) ----
__global__ __launch_bounds__(256) void tokslot_kernel(const int* __restrict__ tokIdx,
                                                      int* __restrict__ countsI,
                                                      int* __restrict__ slotOf) {
    int t = blockIdx.x * 256 + threadIdx.x;
    int k = tokIdx[t];
    slotOf[t] = atomicAdd(countsI + k, 1);
}

// ---- CSR pass 2: exclusive scan of countsI[4096] -> offs ----
__global__ __launch_bounds__(256) void scan_kernel(const int* __restrict__ countsI,
                                                   int* __restrict__ offs) {
    __shared__ int part[256];
    __shared__ int pref[257];
    int tid = threadIdx.x;
    int local[16];
    int s = 0;
    #pragma unroll
    for (int i = 0; i < 16; ++i) { local[i] = countsI[tid * 16 + i]; s += local[i]; }
    part[tid] = s;
    __syncthreads();
    if (tid == 0) {
        pref[0] = 0;
        for (int i = 0; i < 256; ++i) pref[i + 1] = pref[i] + part[i];
    }
    __syncthreads();
    int run = pref[tid];
    #pragma unroll
    for (int i = 0; i < 16; ++i) { offs[tid * 16 + i] = run; run += local[i]; }
}

// ---- CSR pass 3: fill token list (no atomics) ----
__global__ __launch_bounds__(256) void filllist_kernel(const int* __restrict__ tokIdx,
                                                       const int* __restrict__ offs,
                                                       const int* __restrict__ slotOf,
                                                       int* __restrict__ tlist) {
    int t = blockIdx.x * 256 + threadIdx.x;
    int k = tokIdx[t];
    tlist[offs[k] + slotOf[t]] = t;
}

// ---- cs_pre = ema_cs*decay + (1-decay)*counts ; n = sum(cs_pre) ----
__global__ __launch_bounds__(256) void cs_kernel(const float* __restrict__ ema_cs,
                                                 const int* __restrict__ countsI,
                                                 float* __restrict__ cs_pre,
                                                 float* __restrict__ nptr) {
    int k = blockIdx.x * 256 + threadIdx.x;
    float c = ema_cs[k] * DECAYF + (1.0f - DECAYF) * (float)countsI[k];
    cs_pre[k] = c;
    float s = c;
    #pragma unroll
    for (int o = 32; o > 0; o >>= 1) s += __shfl_down(s, o);
    __shared__ float red[4];
    int lane = threadIdx.x & 63, w = threadIdx.x >> 6;
    if (lane == 0) red[w] = s;
    __syncthreads();
    if (threadIdx.x == 0) atomicAdd(nptr, red[0] + red[1] + red[2] + red[3]);
}

// ---- per-token scatter: full one-hot row + quantized row (pure streaming) ----
__global__ __launch_bounds__(256) void scatter_kernel(const float* __restrict__ cb,
                                                      const int* __restrict__ tokIdx,
                                                      float* __restrict__ quant,
                                                      float* __restrict__ enc) {
    int tok = blockIdx.x;
    int tid = threadIdx.x;
    int k = tokIdx[tok];
    float4* er = (float4*)(enc + (size_t)tok * KEMB);
    int kf4 = k >> 2, kc = k & 3;
    #pragma unroll
    for (int v = 0; v < 4; ++v) {
        int f4 = v * 256 + tid;
        float4 val = {0.f, 0.f, 0.f, 0.f};
        if (f4 == kf4) ((float*)&val)[kc] = 1.0f;
        er[f4] = val;
    }
    if (tid < 64) {
        float4 e = *(const float4*)(cb + (size_t)k * DDIM + tid * 4);
        *(float4*)(quant + (size_t)tok * DDIM + tid * 4) = e;
    }
}

// ---- balanced segmented dw reduction over the CSR list ----
#define SEG_CHUNK 32
__global__ __launch_bounds__(256) void segdw_kernel(const float* __restrict__ xg,
                                                    const int* __restrict__ tlist,
                                                    const int* __restrict__ tokIdx,
                                                    float* __restrict__ dw) {
    int tid = threadIdx.x;
    int s0 = blockIdx.x * SEG_CHUNK;
    float acc = 0.0f;
    int curk = -1;
    for (int s = s0; s < s0 + SEG_CHUNK; ++s) {
        int t = tlist[s];
        int k = tokIdx[t];
        if (k != curk) {
            if (curk >= 0) atomicAdd(dw + (size_t)curk * DDIM + tid, acc);
            acc = 0.0f;
            curk = k;
        }
        acc += xg[(size_t)t * DDIM + tid];
    }
    if (curk >= 0) atomicAdd(dw + (size_t)curk * DDIM + tid, acc);
}

// ---- epilogue: new_ema_w, laplace-smoothed cs, new_codebook ----
__global__ __launch_bounds__(256) void epi_kernel(const float* __restrict__ ema_w,
                                                  const float* __restrict__ dw,
                                                  const float* __restrict__ cs_pre,
                                                  const float* __restrict__ nptr,
                                                  float* __restrict__ new_cb,
                                                  float* __restrict__ new_w,
                                                  float* __restrict__ cs_out) {
    int gid = blockIdx.x * 256 + threadIdx.x;   // 0 .. 1048575
    int k = gid >> 8, d = gid & 255;
    float n = *nptr;
    float csp = cs_pre[k];
    float cs = (csp + EPSF) / (n + (float)KEMB * EPSF) * n;
    float w = ema_w[gid] * DECAYF + (1.0f - DECAYF) * dw[gid];
    new_w[gid] = w;
    new_cb[gid] = w / cs;
    if (d == 0) cs_out[k] = cs;
}

extern "C" void kernel_launch(void* const* d_in, const int* in_sizes, int n_in,
                              void* d_out, int out_size, void* d_ws, size_t ws_size,
                              hipStream_t stream) {
    const float* xg     = (const float*)d_in[0];   // [32768,256]
    const float* cbg    = (const float*)d_in[1];   // [4096,256]
    const float* ema_w  = (const float*)d_in[2];   // [4096,256]
    const float* ema_cs = (const float*)d_in[3];   // [4096]

    float* out = (float*)d_out;
    unsigned char* wsb = (unsigned char*)d_ws;

    float* quant  = out + OFF_Q;
    float* enc    = out + OFF_E;
    float* new_cb = out + OFF_CB;
    float* new_w  = out + OFF_W;
    float* cs_out = out + OFF_CS;

    _Float16* Ahat = (_Float16*)(wsb + B_AHAT);
    _Float16* Bhat = (_Float16*)(wsb + B_BHAT);
    float4* part   = (float4*)(wsb + B_PART);
    float* ce      = (float*)(wsb + B_CE);
    int*   countsI = (int*)(wsb + B_CNTI);
    float* cs_pre  = (float*)(wsb + B_CSP);
    int*   offs    = (int*)(wsb + B_OFFS);
    float* nptr    = (float*)(wsb + B_NPTR);
    int*   flagCnt = (int*)(wsb + B_NPTR + 4);
    int*   tokIdx  = (int*)(wsb + B_TIDX);
    int*   flist   = (int*)(wsb + B_FLIST);
    int*   slotOf  = (int*)(wsb + B_SLOT);
    int*   tlist   = (int*)(wsb + B_TLIST);
    float* dw      = (float*)(wsb + B_DW);

    // zero-init (d_out / d_ws are poisoned with 0xAA before every call).
    hipMemsetAsync(countsI, 0, KEMB * sizeof(int), stream);
    hipMemsetAsync(nptr, 0, 8, stream);                        // n + flagCount
    hipMemsetAsync(dw, 0, (size_t)KEMB * DDIM * sizeof(float), stream);

    cast16_kernel<<<(NTOK * DDIM / 8) / 256, 256, 0, stream>>>(xg, Ahat);
    cast16_kernel<<<(KEMB * DDIM / 8) / 256, 256, 0, stream>>>(cbg, Bhat);
    ce_kernel<<<KEMB / 4, 256, 0, stream>>>(cbg, ce);
    gemm_argmin_kernel<<<dim3(KEMB / 128, NTOK / 128), 256, 0, stream>>>(Ahat, Bhat, ce, part);
    argmin_reduce_kernel<<<NTOK / 4, 256, 0, stream>>>(part, tokIdx, flist, flagCnt);
    refine_kernel<<<256, 256, 0, stream>>>(xg, cbg, part, tokIdx, flist, flagCnt);
    tokslot_kernel<<<NTOK / 256, 256, 0, stream>>>(tokIdx, countsI, slotOf);
    cs_kernel<<<KEMB / 256, 256, 0, stream>>>(ema_cs, countsI, cs_pre, nptr);
    scan_kernel<<<1, 256, 0, stream>>>(countsI, offs);
    filllist_kernel<<<NTOK / 256, 256, 0, stream>>>(tokIdx, offs, slotOf, tlist);
    scatter_kernel<<<NTOK, 256, 0, stream>>>(cbg, tokIdx, quant, enc);
    segdw_kernel<<<NTOK / SEG_CHUNK, 256, 0, stream>>>(xg, tlist, tokIdx, dw);
    epi_kernel<<<(KEMB * DDIM) / 256, 256, 0, stream>>>(ema_w, dw, cs_pre, nptr,
                                                        new_cb, new_w, cs_out);
}